// Round 7
// baseline (426.139 us; speedup 1.0000x reference)
//
#include <hip/hip_runtime.h>

// CSR SpMV: y[r] = sum_{j in [ro[r], ro[r+1])} sx[j] * x[sel[j]]
// NNZ = 32M, ROWS = 1M (+1 offsets), COLS = 1M.
//
// R7 vs R6: four gather structures all ~258-273us => structural wall at
// ~5 cy/divergent-lane-request/CU. Model: every 4B x-gather misses L1 and
// fills a 64B line over the XCD L2->TCP fabric (2GB fill traffic/dispatch,
// ~7.9 TB/s = fabric ceiling). Fix: gathers become NON-TEMPORAL (nt bit,
// no L1 allocate -> 4B-granular L2 service). Structure reverted to lean R5
// (register gathers, no slab).

constexpr int ITEMS     = 16;              // nnz per thread
constexpr int BLOCK     = 256;
constexpr int CHUNK_NNZ = BLOCK * ITEMS;   // 4096 nnz per block
constexpr int SRO_CAP   = 4098;            // LDS row-offset cache (16.4 KB)

typedef float f32x4 __attribute__((ext_vector_type(4)));
typedef int   i32x4 __attribute__((ext_vector_type(4)));

__global__ __launch_bounds__(256) void zero_out(float* __restrict__ y, int n) {
    int i = blockIdx.x * blockDim.x + threadIdx.x;
    if (i < n) y[i] = 0.0f;
}

// upper_bound over ro[1..num_rows], returns row r with ro[r] <= key < ro[r+1]
__device__ __forceinline__ int row_of(const int* __restrict__ ro,
                                      int num_rows, int key) {
    int left = 1, right = num_rows;
    while (left < right) {
        int mid = (left + right) >> 1;
        if (ro[mid] <= key) left = mid + 1; else right = mid;
    }
    return left - 1;
}

__global__ __launch_bounds__(BLOCK) void spmv_chunk(
    const float* __restrict__ sx,
    const float* __restrict__ x,
    const int*   __restrict__ sel,
    const int*   __restrict__ ro,   // length num_rows+1, ro[0]=0, ro[nr]=nnz
    float*       __restrict__ y,
    int nnz, int num_rows)
{
    __shared__ int sro[SRO_CAP];
    __shared__ int s_lo, s_hi;

    const int b  = blockIdx.x;
    const int B0 = b * CHUNK_NNZ;
    const int B1 = min(nnz, B0 + CHUNK_NNZ);

    if (threadIdx.x == 0)         s_lo = row_of(ro, num_rows, B0);
    if (threadIdx.x == BLOCK - 1) s_hi = row_of(ro, num_rows, B1 - 1);
    __syncthreads();

    const int lo = s_lo;
    const int n  = s_hi + 2 - lo;        // cache ro[lo .. hi+1], n entries
    const bool use_lds = (n <= SRO_CAP);
    if (use_lds) {
        for (int i = threadIdx.x; i < n; i += BLOCK) sro[i] = ro[lo + i];
    }
    __syncthreads();

    const int j0 = (b * BLOCK + threadIdx.x) * ITEMS;
    if (j0 >= nnz) return;               // after all barriers — safe
    const int j1 = min(nnz, j0 + ITEMS);

    float sum = 0.0f;

    if (use_lds && j1 - j0 == ITEMS) {
        // Phase 0: row start via LDS binary search
        int left = 1, right = n - 1;
        while (left < right) {
            int mid = (left + right) >> 1;
            if (sro[mid] <= j0) left = mid + 1; else right = mid;
        }
        int r_local  = left - 1;
        int row_end  = sro[r_local + 1];

        // Phase 1a: load all 16 indices (nt), issue 16 NON-TEMPORAL gathers
        // (nt => no L1 line allocate; 4B-granular service from L2).
        i32x4 c[ITEMS / 4];
        #pragma unroll
        for (int v = 0; v < ITEMS / 4; ++v) {
            c[v] = __builtin_nontemporal_load(
                       reinterpret_cast<const i32x4*>(sel + j0) + v);
        }
        float p[ITEMS];
        #pragma unroll
        for (int v = 0; v < ITEMS / 4; ++v) {
            #pragma unroll
            for (int k = 0; k < 4; ++k) {
                p[v * 4 + k] = __builtin_nontemporal_load(x + c[v][k]);
            }
        }
        __builtin_amdgcn_sched_barrier(0);   // keep all 16 gathers issued first

        // Phase 1b: stream sx (nt) and multiply.
        f32x4 s[ITEMS / 4];
        #pragma unroll
        for (int v = 0; v < ITEMS / 4; ++v) {
            s[v] = __builtin_nontemporal_load(
                       reinterpret_cast<const f32x4*>(sx + j0) + v);
        }
        #pragma unroll
        for (int v = 0; v < ITEMS / 4; ++v) {
            #pragma unroll
            for (int k = 0; k < 4; ++k) {
                p[v * 4 + k] *= s[v][k];
            }
        }

        // Phase 2: row-walk accumulation, offsets from LDS, atomic per row.
        #pragma unroll
        for (int k = 0; k < ITEMS; ++k) {
            int jj = j0 + k;
            while (jj >= row_end) {              // handles empty rows
                if (sum != 0.0f) atomicAdd(&y[lo + r_local], sum);
                sum = 0.0f;
                ++r_local;
                row_end = sro[r_local + 1];
            }
            sum += p[k];
        }
        if (sum != 0.0f) atomicAdd(&y[lo + r_local], sum);
    } else {
        // Fallback (row-range exceeded LDS cap, or partial tail chunk).
        int r       = row_of(ro, num_rows, j0);
        int row_end = ro[r + 1];
        for (int j = j0; j < j1; ++j) {
            while (j >= row_end) {
                if (sum != 0.0f) atomicAdd(&y[r], sum);
                sum = 0.0f;
                ++r;
                row_end = ro[r + 1];
            }
            sum += sx[j] * x[sel[j]];
        }
        if (sum != 0.0f) atomicAdd(&y[r], sum);
    }
}

extern "C" void kernel_launch(void* const* d_in, const int* in_sizes, int n_in,
                              void* d_out, int out_size, void* d_ws, size_t ws_size,
                              hipStream_t stream) {
    const float* sx  = (const float*)d_in[0];
    const float* x   = (const float*)d_in[1];
    // d_in[2] is the zero "y" input — unused; we zero d_out ourselves.
    const int*   sel = (const int*)d_in[3];
    const int*   ro  = (const int*)d_in[4];
    float*       y   = (float*)d_out;

    const int nnz      = in_sizes[0];
    const int num_rows = in_sizes[4] - 1;   // == out_size

    {
        int threads = 256;
        int blocks  = (out_size + threads - 1) / threads;
        zero_out<<<blocks, threads, 0, stream>>>(y, out_size);
    }
    {
        int blocks = (nnz + CHUNK_NNZ - 1) / CHUNK_NNZ;
        spmv_chunk<<<blocks, BLOCK, 0, stream>>>(sx, x, sel, ro, y, nnz, num_rows);
    }
}

// Round 8
// 229.399 us; speedup vs baseline: 1.8576x; 1.8576x over previous
//
#include <hip/hip_runtime.h>

// CSR SpMV: y[r] = sum_{j in [ro[r], ro[r+1])} sx[j] * x[sel[j]]
// NNZ = 32M, ROWS = 1M (+1 offsets), COLS = 1M.
//
// R8. Established by R1-R7: wall = L2 divergent-request service rate
// (~40M requests/dispatch at ~0.5 req/cy/channel ~= 258us). x-gathers are
// 32M of those and irreducible (random, L2-resident only; R7 proved L2
// service by nt-falsification: FETCH 231->783MB, 426us). This round removes
// the last reducible term: ~3M global atomics -> LDS row accumulation with
// plain coalesced stores for block-interior rows and global atomicAdd only
// for the 2 block-boundary rows.

constexpr int ITEMS     = 16;              // nnz per thread
constexpr int BLOCK     = 256;
constexpr int CHUNK_NNZ = BLOCK * ITEMS;   // 4096 nnz per block
constexpr int SRO_CAP   = 1538;            // ro cache entries (6.2 KB)
constexpr int ACC_CAP   = SRO_CAP - 1;     // row accumulators (6.1 KB)
// rows per 4096-nnz window ~ Poisson(128); P(>1536) ~ 0. Fallback kept.

typedef float f32x4 __attribute__((ext_vector_type(4)));
typedef int   i32x4 __attribute__((ext_vector_type(4)));

__global__ __launch_bounds__(256) void zero_out(float* __restrict__ y, int n) {
    int i = blockIdx.x * blockDim.x + threadIdx.x;
    if (i < n) y[i] = 0.0f;
}

// upper_bound over ro[1..num_rows], returns row r with ro[r] <= key < ro[r+1]
__device__ __forceinline__ int row_of(const int* __restrict__ ro,
                                      int num_rows, int key) {
    int left = 1, right = num_rows;
    while (left < right) {
        int mid = (left + right) >> 1;
        if (ro[mid] <= key) left = mid + 1; else right = mid;
    }
    return left - 1;
}

__global__ __launch_bounds__(BLOCK) void spmv_chunk(
    const float* __restrict__ sx,
    const float* __restrict__ x,
    const int*   __restrict__ sel,
    const int*   __restrict__ ro,   // length num_rows+1, ro[0]=0, ro[nr]=nnz
    float*       __restrict__ y,
    int nnz, int num_rows)
{
    __shared__ int   sro[SRO_CAP];
    __shared__ float acc[ACC_CAP];
    __shared__ int   s_lo, s_hi;

    const int b  = blockIdx.x;
    const int B0 = b * CHUNK_NNZ;
    const int B1 = min(nnz, B0 + CHUNK_NNZ);

    if (threadIdx.x == 0)         s_lo = row_of(ro, num_rows, B0);
    if (threadIdx.x == BLOCK - 1) s_hi = row_of(ro, num_rows, B1 - 1);
    __syncthreads();

    const int lo = s_lo;
    const int n  = s_hi + 2 - lo;        // cache ro[lo .. hi+1], n entries
    const int nrows = n - 1;             // rows lo..hi -> acc[0..nrows-1]
    const bool use_lds = (n <= SRO_CAP);
    if (use_lds) {
        for (int i = threadIdx.x; i < n; i += BLOCK) sro[i] = ro[lo + i];
        for (int i = threadIdx.x; i < nrows; i += BLOCK) acc[i] = 0.0f;
    }
    __syncthreads();

    const int  j0     = (b * BLOCK + threadIdx.x) * ITEMS;
    const bool active = (j0 < nnz);   // NNZ%16==0 -> active => full chunk.
                                      // No early return: barriers below.

    if (use_lds) {
        if (active) {
            // Phase 0: row start via LDS binary search
            int left = 1, right = n - 1;
            while (left < right) {
                int mid = (left + right) >> 1;
                if (sro[mid] <= j0) left = mid + 1; else right = mid;
            }
            int r_local = left - 1;
            int row_end = sro[r_local + 1];

            // Phase 1a: load 16 indices (nt), issue ALL 16 x-gathers
            // (plain loads: x must stay L2-cached — R7 lesson).
            i32x4 c[ITEMS / 4];
            #pragma unroll
            for (int v = 0; v < ITEMS / 4; ++v) {
                c[v] = __builtin_nontemporal_load(
                           reinterpret_cast<const i32x4*>(sel + j0) + v);
            }
            float p[ITEMS];
            #pragma unroll
            for (int v = 0; v < ITEMS / 4; ++v) {
                #pragma unroll
                for (int k = 0; k < 4; ++k) {
                    p[v * 4 + k] = x[c[v][k]];
                }
            }
            __builtin_amdgcn_sched_barrier(0);

            // Phase 1b: stream sx (nt) and multiply.
            f32x4 s[ITEMS / 4];
            #pragma unroll
            for (int v = 0; v < ITEMS / 4; ++v) {
                s[v] = __builtin_nontemporal_load(
                           reinterpret_cast<const f32x4*>(sx + j0) + v);
            }
            #pragma unroll
            for (int v = 0; v < ITEMS / 4; ++v) {
                #pragma unroll
                for (int k = 0; k < 4; ++k) {
                    p[v * 4 + k] *= s[v][k];
                }
            }

            // Phase 2: row-walk, flush partials into LDS accumulators.
            float sum = 0.0f;
            #pragma unroll
            for (int k = 0; k < ITEMS; ++k) {
                int jj = j0 + k;
                while (jj >= row_end) {              // handles empty rows
                    if (sum != 0.0f) atomicAdd(&acc[r_local], sum);
                    sum = 0.0f;
                    ++r_local;
                    row_end = sro[r_local + 1];
                }
                sum += p[k];
            }
            if (sum != 0.0f) atomicAdd(&acc[r_local], sum);
        }

        __syncthreads();

        // Phase 3: cooperative flush. Rows lo+1..hi-1 are exclusive to this
        // block -> plain store (y pre-zeroed; single writer). Rows lo and hi
        // may be shared with neighbor blocks -> global atomicAdd.
        for (int i = threadIdx.x; i < nrows; i += BLOCK) {
            float v = acc[i];
            if (i == 0 || i == nrows - 1) {
                if (v != 0.0f) atomicAdd(&y[lo + i], v);
            } else {
                y[lo + i] = v;
            }
        }
    } else if (active) {
        // Fallback (row-range exceeded SRO_CAP; P ~ 0 for this data).
        int r       = row_of(ro, num_rows, j0);
        int row_end = ro[r + 1];
        float sum = 0.0f;
        for (int j = j0; j < min(nnz, j0 + ITEMS); ++j) {
            while (j >= row_end) {
                if (sum != 0.0f) atomicAdd(&y[r], sum);
                sum = 0.0f;
                ++r;
                row_end = ro[r + 1];
            }
            sum += sx[j] * x[sel[j]];
        }
        if (sum != 0.0f) atomicAdd(&y[r], sum);
    }
}

extern "C" void kernel_launch(void* const* d_in, const int* in_sizes, int n_in,
                              void* d_out, int out_size, void* d_ws, size_t ws_size,
                              hipStream_t stream) {
    const float* sx  = (const float*)d_in[0];
    const float* x   = (const float*)d_in[1];
    // d_in[2] is the zero "y" input — unused; we zero d_out ourselves.
    const int*   sel = (const int*)d_in[3];
    const int*   ro  = (const int*)d_in[4];
    float*       y   = (float*)d_out;

    const int nnz      = in_sizes[0];
    const int num_rows = in_sizes[4] - 1;   // == out_size

    {
        int threads = 256;
        int blocks  = (out_size + threads - 1) / threads;
        zero_out<<<blocks, threads, 0, stream>>>(y, out_size);
    }
    {
        int blocks = (nnz + CHUNK_NNZ - 1) / CHUNK_NNZ;
        spmv_chunk<<<blocks, BLOCK, 0, stream>>>(sx, x, sel, ro, y, nnz, num_rows);
    }
}